// Round 1
// baseline (825.179 us; speedup 1.0000x reference)
//
#include <hip/hip_runtime.h>

// SNN: 3-layer LIF, B=256, T=32, H=1024, IN=2312, OUT=10.
// Factorization: per-layer GEMM over all (t,b) rows at once, then a
// parallel-over-neurons sequential-over-t LIF scan. 6 kernels total.

#define TB 256
#define TT 32
#define TH 1024
#define TIN 2312
#define TOUT 10
#define TM (TT * TB)  // 8192 rows = (t,b)

// C[r][n] = sum_k A_row(r)[k] * W[n][k] + bias[n]
// A row byte offset = (r/256)*sT + (r%256)*sB   (handles x's (B,T,IN) layout)
template <int BM, int BN, int KT>
__global__ __launch_bounds__(256) void gemm_nt(
    const float* __restrict__ A, long sT, long sB,
    const float* __restrict__ Wt, const float* __restrict__ bias,
    float* __restrict__ C, int N, int K) {
  constexpr int PAD = 4;
  __shared__ float As[KT][BM + PAD];
  __shared__ float Bs[KT][BN + PAD];

  const int tid = threadIdx.x;
  const int tx = tid & 15, ty = tid >> 4;
  const int m0 = blockIdx.x * BM, n0 = blockIdx.y * BN;

  // Per-thread load assignments: idx = p*256+tid; element k4=(idx&3)*4, row=idx>>2
  const int k4 = (tid & 3) * 4;
  const float* apt[2];
  const float* bpt[2];
  int mc[2];
  #pragma unroll
  for (int p = 0; p < 2; ++p) {
    int idx = p * 256 + tid;
    int m = idx >> 2;
    mc[p] = m;
    int r = m0 + m;
    apt[p] = A + (long)(r >> 8) * sT + (long)(r & 255) * sB + k4;
    bpt[p] = Wt + (long)(n0 + m) * K + k4;
  }

  float acc[8][8];
  #pragma unroll
  for (int i = 0; i < 8; ++i)
    #pragma unroll
    for (int j = 0; j < 8; ++j) acc[i][j] = 0.f;

  const int numKT = (K + KT - 1) / KT;
  for (int kt = 0; kt < numKT; ++kt) {
    const int kb = kt * KT;
    const bool full = (kb + k4 + 4 <= K);
    float4 av[2], bv[2];
    #pragma unroll
    for (int p = 0; p < 2; ++p) {
      av[p] = full ? *(const float4*)(apt[p] + kb) : float4{0.f, 0.f, 0.f, 0.f};
      bv[p] = full ? *(const float4*)(bpt[p] + kb) : float4{0.f, 0.f, 0.f, 0.f};
    }
    __syncthreads();  // previous iter's LDS reads done
    #pragma unroll
    for (int p = 0; p < 2; ++p) {
      As[k4 + 0][mc[p]] = av[p].x;
      As[k4 + 1][mc[p]] = av[p].y;
      As[k4 + 2][mc[p]] = av[p].z;
      As[k4 + 3][mc[p]] = av[p].w;
      Bs[k4 + 0][mc[p]] = bv[p].x;
      Bs[k4 + 1][mc[p]] = bv[p].y;
      Bs[k4 + 2][mc[p]] = bv[p].z;
      Bs[k4 + 3][mc[p]] = bv[p].w;
    }
    __syncthreads();
    #pragma unroll
    for (int kk = 0; kk < KT; ++kk) {
      float a[8], b[8];
      *(float4*)&a[0] = *(const float4*)&As[kk][ty * 8];
      *(float4*)&a[4] = *(const float4*)&As[kk][ty * 8 + 4];
      *(float4*)&b[0] = *(const float4*)&Bs[kk][tx * 8];
      *(float4*)&b[4] = *(const float4*)&Bs[kk][tx * 8 + 4];
      #pragma unroll
      for (int i = 0; i < 8; ++i)
        #pragma unroll
        for (int j = 0; j < 8; ++j) acc[i][j] = fmaf(a[i], b[j], acc[i][j]);
    }
  }

  float bb[8];
  *(float4*)&bb[0] = *(const float4*)&bias[n0 + tx * 8];
  *(float4*)&bb[4] = *(const float4*)&bias[n0 + tx * 8 + 4];
  #pragma unroll
  for (int i = 0; i < 8; ++i) {
    int r = m0 + ty * 8 + i;
    float* crow = C + (long)r * N + n0 + tx * 8;
    float4 c0, c1;
    c0.x = acc[i][0] + bb[0]; c0.y = acc[i][1] + bb[1];
    c0.z = acc[i][2] + bb[2]; c0.w = acc[i][3] + bb[3];
    c1.x = acc[i][4] + bb[4]; c1.y = acc[i][5] + bb[5];
    c1.z = acc[i][6] + bb[6]; c1.w = acc[i][7] + bb[7];
    *(float4*)(crow) = c0;
    *(float4*)(crow + 4) = c1;
  }
}

// LIF scan: one thread per (b,h); buf[t*stride + idx] holds input current,
// overwritten in place with the spike (0/1).
__global__ __launch_bounds__(256) void lif_scan(float* __restrict__ buf,
                                                int stride, int n) {
  int idx = blockIdx.x * blockDim.x + threadIdx.x;
  if (idx >= n) return;
  float v = 0.f, cur = 0.f;
  float* p = buf + idx;
  #pragma unroll
  for (int t = 0; t < TT; ++t) {
    float inp = p[(long)t * stride];
    float vd = fmaf(0.05f, cur - v, v);  // v + dt/tau_mem * (i - v)
    float id = cur - 0.2f * cur;         // i - dt/tau_syn * i
    float s = (vd > 1.0f) ? 1.0f : 0.f;  // == (vd - 1 > 0), exact for fp32
    v = (1.0f - s) * vd;
    cur = id + inp;
    p[(long)t * stride] = s;
  }
}

// GEMM3: one wave per row r; I3[r][o] = S2[r][:] . Wout[o][:] + bout[o]
__global__ __launch_bounds__(256) void gemm3_kernel(
    const float* __restrict__ S2, const float* __restrict__ Wout,
    const float* __restrict__ bout, float* __restrict__ I3) {
  int wave = (blockIdx.x * blockDim.x + threadIdx.x) >> 6;
  int lane = threadIdx.x & 63;
  if (wave >= TM) return;
  const float* srow = S2 + (long)wave * TH;
  float acc[TOUT];
  #pragma unroll
  for (int o = 0; o < TOUT; ++o) acc[o] = 0.f;
  for (int k = lane; k < TH; k += 64) {
    float s = srow[k];
    #pragma unroll
    for (int o = 0; o < TOUT; ++o) acc[o] = fmaf(s, Wout[o * TH + k], acc[o]);
  }
  #pragma unroll
  for (int off = 32; off > 0; off >>= 1)
    #pragma unroll
    for (int o = 0; o < TOUT; ++o) acc[o] += __shfl_down(acc[o], off, 64);
  if (lane == 0) {
    #pragma unroll
    for (int o = 0; o < TOUT; ++o) I3[(long)wave * TOUT + o] = acc[o] + bout[o];
  }
}

// Output-layer LIF scan + rate decode: one thread per (b,o).
__global__ __launch_bounds__(256) void scan_out(const float* __restrict__ I3,
                                                float* __restrict__ out) {
  int idx = blockIdx.x * blockDim.x + threadIdx.x;
  if (idx >= TB * TOUT) return;
  float v = 0.f, cur = 0.f, cnt = 0.f;
  #pragma unroll
  for (int t = 0; t < TT; ++t) {
    float inp = I3[(long)t * (TB * TOUT) + idx];
    float vd = fmaf(0.05f, cur - v, v);
    float id = cur - 0.2f * cur;
    float s = (vd > 1.0f) ? 1.0f : 0.f;
    v = (1.0f - s) * vd;
    cur = id + inp;
    cnt += s;
  }
  out[idx] = cnt;
}

extern "C" void kernel_launch(void* const* d_in, const int* in_sizes, int n_in,
                              void* d_out, int out_size, void* d_ws,
                              size_t ws_size, hipStream_t stream) {
  const float* x    = (const float*)d_in[0];  // (B,T,2,34,34) = (256,32,2312)
  const float* W1   = (const float*)d_in[1];  // (1024,2312)
  const float* b1   = (const float*)d_in[2];
  const float* W2   = (const float*)d_in[3];  // (1024,1024)
  const float* b2   = (const float*)d_in[4];
  const float* Wout = (const float*)d_in[5];  // (10,1024)
  const float* bout = (const float*)d_in[6];

  float* buf1 = (float*)d_ws;                       // TM*TH: I1 -> S1 in place
  float* buf2 = buf1 + (size_t)TM * TH;             // TM*TH: I2 -> S2 in place
  float* buf3 = buf2 + (size_t)TM * TH;             // TM*TOUT

  // GEMM1: row r=(t,b) -> x offset (b*T + t)*IN floats
  gemm_nt<128, 128, 16><<<dim3(TM / 128, TH / 128), 256, 0, stream>>>(
      x, (long)TIN, (long)TT * TIN, W1, b1, buf1, TH, TIN);

  lif_scan<<<(TB * TH) / 256, 256, 0, stream>>>(buf1, TB * TH, TB * TH);

  // GEMM2: row r contiguous in S1: offset = r*TH = (r/256)*(256*TH) + (r%256)*TH
  gemm_nt<128, 128, 16><<<dim3(TM / 128, TH / 128), 256, 0, stream>>>(
      buf1, (long)TB * TH, (long)TH, W2, b2, buf2, TH, TH);

  lif_scan<<<(TB * TH) / 256, 256, 0, stream>>>(buf2, TB * TH, TB * TH);

  gemm3_kernel<<<(TM * 64) / 256, 256, 0, stream>>>(buf2, Wout, bout, buf3);

  scan_out<<<(TB * TOUT + 255) / 256, 256, 0, stream>>>(buf3, (float*)d_out);
}

// Round 2
// 416.001 us; speedup vs baseline: 1.9836x; 1.9836x over previous
//
#include <hip/hip_runtime.h>

// SNN: 3-layer LIF, B=256, T=32, H=1024, IN=2312, OUT=10.
// GEMMs run on MFMA (bf16) via exact 3-way bf16 splitting of fp32 operands:
//   x = x0+x1+x2 (exact), W = w0+w1+w2 (exact); keep pairs pa+pb<=2 (6 pairs)
//   -> error below fp32 accumulation noise. Spikes are {0,1} = exact bf16,
//   so GEMM2 needs only 3 pairs (1 A-plane x 3 W-planes), fully exact.
// GEMM1 fuses the x-split into LDS staging (no materialized x planes):
//   96 MFMA/wave per barrier (vs m97's 16) -> barrier drain amortized.

#define TB 256
#define TT 32
#define TH 1024
#define TIN 2312
#define TOUT 10
#define TM (TT * TB)   // 8192 rows = (t,b)
#define KP1 2368       // TIN padded to multiple of 32

typedef __bf16 bf16_t;
typedef bf16_t bf16x8 __attribute__((ext_vector_type(8)));
typedef bf16_t bf16x4 __attribute__((ext_vector_type(4)));
typedef float floatx4 __attribute__((ext_vector_type(4)));

__device__ __forceinline__ void split3(float v, bf16_t& a, bf16_t& b, bf16_t& c) {
  a = (bf16_t)v;
  float r1 = v - (float)a;   // exact (Sterbenz)
  b = (bf16_t)r1;
  c = (bf16_t)(r1 - (float)b);
}

// W (rows x K) -> 3 bf16 planes (rows x Kp), zero-padded K..Kp.
__global__ __launch_bounds__(256) void split_w(const float* __restrict__ W,
                                               bf16_t* __restrict__ P,
                                               long plane, int K, int Kp) {
  int k4 = (blockIdx.x * 256 + threadIdx.x) * 4;
  if (k4 >= Kp) return;
  long r = blockIdx.y;
  float4 v = (k4 < K) ? *(const float4*)(W + r * (long)K + k4)
                      : float4{0.f, 0.f, 0.f, 0.f};
  float t[4] = {v.x, v.y, v.z, v.w};
  bf16x4 a, b, c;
  #pragma unroll
  for (int e = 0; e < 4; ++e) {
    bf16_t x, y, z;
    split3(t[e], x, y, z);
    a[e] = x; b[e] = y; c[e] = z;
  }
  long o = r * (long)Kp + k4;
  *(bf16x4*)(P + o) = a;
  *(bf16x4*)(P + plane + o) = b;
  *(bf16x4*)(P + 2 * plane + o) = c;
}

// C[r][n] = sum_pairs sum_k Apa[r][k]*Bpb[n][k] + bias[n]
// A row element offset = (r>>8)*sT + (r&255)*sB.
// AF32: A is fp32, split 3-way into LDS during staging (APL=3, 6 pairs).
// else: A is bf16 (exact spikes), APL=1, 3 pairs.
template <bool AF32>
__global__ __launch_bounds__(256, 2) void snn_gemm(
    const float* __restrict__ Af, const bf16_t* __restrict__ Ab,
    long sT, long sB, const bf16_t* __restrict__ Bp, long planeB,
    int Kp, int K, const float* __restrict__ bias,
    float* __restrict__ C, int N) {
  constexpr int APL = AF32 ? 3 : 1;
  __shared__ bf16_t As[APL][128 * 32];  // [m][k] row-major, 8KB/plane
  __shared__ bf16_t Bs[3][128 * 32];

  const int tid = threadIdx.x;
  const int wave = tid >> 6, lane = tid & 63;
  const int quad = lane >> 4, l16 = lane & 15;
  const int wm = (wave & 1) * 64, wn = (wave >> 1) * 64;
  const long m0 = (long)blockIdx.x * 128, n0 = (long)blockIdx.y * 128;

  floatx4 acc[4][4];
  #pragma unroll
  for (int i = 0; i < 4; ++i)
    #pragma unroll
    for (int j = 0; j < 4; ++j) acc[i][j] = (floatx4){0.f, 0.f, 0.f, 0.f};

  // staging chunks: c = p*256+tid -> tile row c>>2, k-offset (c&3)*8 (16B)
  float4 xv[2][2];
  bf16x8 av[2];
  bf16x8 bv[3][2];

  auto prefetch = [&](int kb) {
    #pragma unroll
    for (int p = 0; p < 2; ++p) {
      const int c = p * 256 + tid;
      const long r = m0 + (c >> 2);
      const int k0 = kb + (c & 3) * 8;
      if constexpr (AF32) {
        const float* xr = Af + (r >> 8) * sT + (r & 255) * sB + k0;
        xv[p][0] = (k0 < K) ? *(const float4*)xr : float4{0.f, 0.f, 0.f, 0.f};
        xv[p][1] = (k0 + 4 < K) ? *(const float4*)(xr + 4)
                                : float4{0.f, 0.f, 0.f, 0.f};
      } else {
        av[p] = *(const bf16x8*)(Ab + (r >> 8) * sT + (r & 255) * sB + k0);
      }
    }
    #pragma unroll
    for (int q = 0; q < 3; ++q)
      #pragma unroll
      for (int p = 0; p < 2; ++p) {
        const int c = p * 256 + tid;
        bv[q][p] = *(const bf16x8*)(Bp + q * planeB +
                                    (n0 + (c >> 2)) * (long)Kp + kb +
                                    (c & 3) * 8);
      }
  };

  auto commit = [&]() {
    #pragma unroll
    for (int p = 0; p < 2; ++p) {
      const int c = p * 256 + tid;
      if constexpr (AF32) {
        bf16x8 h0, h1, h2;
        float t0[4] = {xv[p][0].x, xv[p][0].y, xv[p][0].z, xv[p][0].w};
        float t1[4] = {xv[p][1].x, xv[p][1].y, xv[p][1].z, xv[p][1].w};
        #pragma unroll
        for (int e = 0; e < 8; ++e) {
          float v = (e < 4) ? t0[e] : t1[e - 4];
          bf16_t a, b, cc;
          split3(v, a, b, cc);
          h0[e] = a; h1[e] = b; h2[e] = cc;
        }
        *(bf16x8*)(&As[0][c * 8]) = h0;
        *(bf16x8*)(&As[1][c * 8]) = h1;
        *(bf16x8*)(&As[2][c * 8]) = h2;
      } else {
        *(bf16x8*)(&As[0][c * 8]) = av[p];
      }
      #pragma unroll
      for (int q = 0; q < 3; ++q) *(bf16x8*)(&Bs[q][c * 8]) = bv[q][p];
    }
  };

  const int numT = Kp / 32;
  prefetch(0);
  for (int kt = 0; kt < numT; ++kt) {
    __syncthreads();   // prior tile's frag reads done
    commit();
    const int kbn = (kt + 1 < numT) ? (kt + 1) * 32 : 0;  // harmless reload
    prefetch(kbn);     // next tile: latency hides behind MFMA phase
    __syncthreads();   // staging visible
    #pragma unroll
    for (int pb = 0; pb < 3; ++pb) {
      bf16x8 bfr[4];
      #pragma unroll
      for (int j = 0; j < 4; ++j)
        bfr[j] = *(const bf16x8*)(&Bs[pb][(wn + j * 16 + l16) * 32 + quad * 8]);
      const int pamax = AF32 ? (2 - pb) : 0;  // pairs with pa+pb<=2
      #pragma unroll
      for (int pa = 0; pa < APL; ++pa) {
        if (pa > pamax) break;
        bf16x8 afr[4];
        #pragma unroll
        for (int i = 0; i < 4; ++i)
          afr[i] =
              *(const bf16x8*)(&As[pa][(wm + i * 16 + l16) * 32 + quad * 8]);
        #pragma unroll
        for (int i = 0; i < 4; ++i)
          #pragma unroll
          for (int j = 0; j < 4; ++j)
            acc[i][j] = __builtin_amdgcn_mfma_f32_16x16x32_bf16(
                afr[i], bfr[j], acc[i][j], 0, 0, 0);
      }
    }
  }

  // epilogue: C/D layout col=lane&15, row=quad*4+reg (m89/m91-verified)
  #pragma unroll
  for (int j = 0; j < 4; ++j) {
    const long col = n0 + wn + j * 16 + l16;
    const float bvv = bias[col];
    #pragma unroll
    for (int i = 0; i < 4; ++i) {
      const long row0 = m0 + wm + i * 16 + quad * 4;
      #pragma unroll
      for (int g = 0; g < 4; ++g)
        C[(row0 + g) * (long)N + col] = acc[i][j][g] + bvv;
    }
  }
}

// LIF scan, fp32 in -> bf16 spikes out (spikes {0,1} exact in bf16).
__global__ __launch_bounds__(256) void lif_scan_bf16(const float* __restrict__ I,
                                                     bf16_t* __restrict__ S) {
  int idx = blockIdx.x * 256 + threadIdx.x;
  float v = 0.f, cur = 0.f;
  #pragma unroll
  for (int t = 0; t < TT; ++t) {
    float inp = I[(long)t * (TB * TH) + idx];
    float vd = fmaf(0.05f, cur - v, v);
    float id = cur - 0.2f * cur;
    float s = (vd > 1.0f) ? 1.0f : 0.f;
    v = (1.0f - s) * vd;
    cur = id + inp;
    S[(long)t * (TB * TH) + idx] = (bf16_t)s;
  }
}

// LIF scan in-place fp32 (layer 2 output for tiny GEMM3).
__global__ __launch_bounds__(256) void lif_scan(float* __restrict__ buf,
                                                int stride, int n) {
  int idx = blockIdx.x * blockDim.x + threadIdx.x;
  if (idx >= n) return;
  float v = 0.f, cur = 0.f;
  float* p = buf + idx;
  #pragma unroll
  for (int t = 0; t < TT; ++t) {
    float inp = p[(long)t * stride];
    float vd = fmaf(0.05f, cur - v, v);
    float id = cur - 0.2f * cur;
    float s = (vd > 1.0f) ? 1.0f : 0.f;
    v = (1.0f - s) * vd;
    cur = id + inp;
    p[(long)t * stride] = s;
  }
}

// GEMM3: one wave per row; I3[r][o] = S2[r][:] . Wout[o][:] + bout[o]
__global__ __launch_bounds__(256) void gemm3_kernel(
    const float* __restrict__ S2, const float* __restrict__ Wout,
    const float* __restrict__ bout, float* __restrict__ I3) {
  int wv = (blockIdx.x * blockDim.x + threadIdx.x) >> 6;
  int lane = threadIdx.x & 63;
  if (wv >= TM) return;
  const float* srow = S2 + (long)wv * TH;
  float acc[TOUT];
  #pragma unroll
  for (int o = 0; o < TOUT; ++o) acc[o] = 0.f;
  for (int k = lane; k < TH; k += 64) {
    float s = srow[k];
    #pragma unroll
    for (int o = 0; o < TOUT; ++o) acc[o] = fmaf(s, Wout[o * TH + k], acc[o]);
  }
  #pragma unroll
  for (int off = 32; off > 0; off >>= 1)
    #pragma unroll
    for (int o = 0; o < TOUT; ++o) acc[o] += __shfl_down(acc[o], off, 64);
  if (lane == 0) {
    #pragma unroll
    for (int o = 0; o < TOUT; ++o) I3[(long)wv * TOUT + o] = acc[o] + bout[o];
  }
}

__global__ __launch_bounds__(256) void scan_out(const float* __restrict__ I3,
                                                float* __restrict__ out) {
  int idx = blockIdx.x * blockDim.x + threadIdx.x;
  if (idx >= TB * TOUT) return;
  float v = 0.f, cur = 0.f, cnt = 0.f;
  #pragma unroll
  for (int t = 0; t < TT; ++t) {
    float inp = I3[(long)t * (TB * TOUT) + idx];
    float vd = fmaf(0.05f, cur - v, v);
    float id = cur - 0.2f * cur;
    float s = (vd > 1.0f) ? 1.0f : 0.f;
    v = (1.0f - s) * vd;
    cur = id + inp;
    cnt += s;
  }
  out[idx] = cnt;
}

extern "C" void kernel_launch(void* const* d_in, const int* in_sizes, int n_in,
                              void* d_out, int out_size, void* d_ws,
                              size_t ws_size, hipStream_t stream) {
  const float* x    = (const float*)d_in[0];  // (256,32,2312)
  const float* W1   = (const float*)d_in[1];  // (1024,2312)
  const float* b1   = (const float*)d_in[2];
  const float* W2   = (const float*)d_in[3];  // (1024,1024)
  const float* b2   = (const float*)d_in[4];
  const float* Wout = (const float*)d_in[5];  // (10,1024)
  const float* bout = (const float*)d_in[6];

  // workspace: W1 planes 14.55MB | W2 planes 6.29MB | I (33.55MB, reused for
  // I1 then I2/S2) | S1 bf16 16.78MB | I3 0.33MB  => 71.5 MB total
  bf16_t* W1p  = (bf16_t*)d_ws;
  bf16_t* W2p  = W1p + 3L * TH * KP1;
  float*  bufI = (float*)(W2p + 3L * TH * TH);
  bf16_t* S1   = (bf16_t*)(bufI + (long)TM * TH);
  float*  buf3 = (float*)(S1 + (long)TM * TH);

  split_w<<<dim3(3, TH), 256, 0, stream>>>(W1, W1p, (long)TH * KP1, TIN, KP1);
  split_w<<<dim3(1, TH), 256, 0, stream>>>(W2, W2p, (long)TH * TH, TH, TH);

  // GEMM1: row r=(t,b): x offset = t*2312 + b*(32*2312)
  snn_gemm<true><<<dim3(TM / 128, TH / 128), 256, 0, stream>>>(
      x, nullptr, (long)TIN, (long)TT * TIN, W1p, (long)TH * KP1, KP1, TIN, b1,
      bufI, TH);

  lif_scan_bf16<<<(TB * TH) / 256, 256, 0, stream>>>(bufI, S1);

  // GEMM2: S1 row-major [8192][1024]: sT=256*1024, sB=1024
  snn_gemm<false><<<dim3(TM / 128, TH / 128), 256, 0, stream>>>(
      nullptr, S1, (long)TB * TH, (long)TH, W2p, (long)TH * TH, TH, TH, b2,
      bufI, TH);

  lif_scan<<<(TB * TH) / 256, 256, 0, stream>>>(bufI, TB * TH, TB * TH);

  gemm3_kernel<<<(TM * 64) / 256, 256, 0, stream>>>(bufI, Wout, bout, buf3);

  scan_out<<<(TB * TOUT + 255) / 256, 256, 0, stream>>>(buf3, (float*)d_out);
}

// Round 3
// 415.509 us; speedup vs baseline: 1.9859x; 1.0012x over previous
//
#include <hip/hip_runtime.h>

// SNN: 3-layer LIF, B=256, T=32, H=1024, IN=2312, OUT=10.
// GEMMs on MFMA (bf16) via exact 3-way bf16 split of fp32 operands
// (pairs pa+pb<=2 => fp32-equivalent; round-2 absmax was 0.0).
// Round-3 changes: LDS row pad 32->36 elements (breaks the 8-way fragment
// read bank conflict -> 2-way = free), and A-fragment dedup (cache
// afr[3][4] per tile, reload only bfr per pb): 36->24 LDS reads/tile (GEMM1),
// 24->16 (GEMM2). Layer-2 spikes emitted as bf16 for the small GEMM3.

#define TB 256
#define TT 32
#define TH 1024
#define TIN 2312
#define TOUT 10
#define TM (TT * TB)   // 8192 rows = (t,b)
#define KP1 2368       // TIN padded to multiple of 32

typedef __bf16 bf16_t;
typedef bf16_t bf16x8 __attribute__((ext_vector_type(8)));
typedef bf16_t bf16x4 __attribute__((ext_vector_type(4)));
typedef float floatx4 __attribute__((ext_vector_type(4)));

__device__ __forceinline__ void split3(float v, bf16_t& a, bf16_t& b, bf16_t& c) {
  a = (bf16_t)v;
  float r1 = v - (float)a;
  b = (bf16_t)r1;
  c = (bf16_t)(r1 - (float)b);
}

// W (rows x K) -> 3 bf16 planes (rows x Kp), zero-padded K..Kp.
__global__ __launch_bounds__(256) void split_w(const float* __restrict__ W,
                                               bf16_t* __restrict__ P,
                                               long plane, int K, int Kp) {
  int k4 = (blockIdx.x * 256 + threadIdx.x) * 4;
  if (k4 >= Kp) return;
  long r = blockIdx.y;
  float4 v = (k4 < K) ? *(const float4*)(W + r * (long)K + k4)
                      : float4{0.f, 0.f, 0.f, 0.f};
  float t[4] = {v.x, v.y, v.z, v.w};
  bf16x4 a, b, c;
  #pragma unroll
  for (int e = 0; e < 4; ++e) {
    bf16_t x, y, z;
    split3(t[e], x, y, z);
    a[e] = x; b[e] = y; c[e] = z;
  }
  long o = r * (long)Kp + k4;
  *(bf16x4*)(P + o) = a;
  *(bf16x4*)(P + plane + o) = b;
  *(bf16x4*)(P + 2 * plane + o) = c;
}

// C[r][n] = sum_pairs sum_k Apa[r][k]*Bpb[n][k] + bias[n]
// A row element offset = (r>>8)*sT + (r&255)*sB.
template <bool AF32>
__global__ __launch_bounds__(256, 2) void snn_gemm(
    const float* __restrict__ Af, const bf16_t* __restrict__ Ab,
    long sT, long sB, const bf16_t* __restrict__ Bp, long planeB,
    int Kp, int K, const float* __restrict__ bias,
    float* __restrict__ C, int N) {
  constexpr int APL = AF32 ? 3 : 1;
  constexpr int LDW = 36;  // 32 + 4 pad: row*18 mod 32 covers all even bank
                           // bases -> fragment reads 2-way (free, m136)
  __shared__ bf16_t As[APL][128 * LDW];
  __shared__ bf16_t Bs[3][128 * LDW];

  const int tid = threadIdx.x;
  const int wave = tid >> 6, lane = tid & 63;
  const int quad = lane >> 4, l16 = lane & 15;
  const int wm = (wave & 1) * 64, wn = (wave >> 1) * 64;
  const long m0 = (long)blockIdx.x * 128, n0 = (long)blockIdx.y * 128;

  floatx4 acc[4][4];
  #pragma unroll
  for (int i = 0; i < 4; ++i)
    #pragma unroll
    for (int j = 0; j < 4; ++j) acc[i][j] = (floatx4){0.f, 0.f, 0.f, 0.f};

  float4 xv[2][2];
  bf16x8 av[2];
  bf16x8 bv[3][2];

  auto prefetch = [&](int kb) {
    #pragma unroll
    for (int p = 0; p < 2; ++p) {
      const int c = p * 256 + tid;
      const long r = m0 + (c >> 2);
      const int k0 = kb + (c & 3) * 8;
      if constexpr (AF32) {
        const float* xr = Af + (r >> 8) * sT + (r & 255) * sB + k0;
        xv[p][0] = (k0 < K) ? *(const float4*)xr : float4{0.f, 0.f, 0.f, 0.f};
        xv[p][1] = (k0 + 4 < K) ? *(const float4*)(xr + 4)
                                : float4{0.f, 0.f, 0.f, 0.f};
      } else {
        av[p] = *(const bf16x8*)(Ab + (r >> 8) * sT + (r & 255) * sB + k0);
      }
    }
    #pragma unroll
    for (int q = 0; q < 3; ++q)
      #pragma unroll
      for (int p = 0; p < 2; ++p) {
        const int c = p * 256 + tid;
        bv[q][p] = *(const bf16x8*)(Bp + q * planeB +
                                    (n0 + (c >> 2)) * (long)Kp + kb +
                                    (c & 3) * 8);
      }
  };

  auto commit = [&]() {
    #pragma unroll
    for (int p = 0; p < 2; ++p) {
      const int c = p * 256 + tid;
      const int off = (c >> 2) * LDW + (c & 3) * 8;
      if constexpr (AF32) {
        bf16x8 h0, h1, h2;
        float t0[4] = {xv[p][0].x, xv[p][0].y, xv[p][0].z, xv[p][0].w};
        float t1[4] = {xv[p][1].x, xv[p][1].y, xv[p][1].z, xv[p][1].w};
        #pragma unroll
        for (int e = 0; e < 8; ++e) {
          float v = (e < 4) ? t0[e] : t1[e - 4];
          bf16_t a, b, cc;
          split3(v, a, b, cc);
          h0[e] = a; h1[e] = b; h2[e] = cc;
        }
        *(bf16x8*)(&As[0][off]) = h0;
        *(bf16x8*)(&As[1][off]) = h1;
        *(bf16x8*)(&As[2][off]) = h2;
      } else {
        *(bf16x8*)(&As[0][off]) = av[p];
      }
      #pragma unroll
      for (int q = 0; q < 3; ++q) *(bf16x8*)(&Bs[q][off]) = bv[q][p];
    }
  };

  const int numT = Kp / 32;
  prefetch(0);
  for (int kt = 0; kt < numT; ++kt) {
    __syncthreads();   // prior tile's frag reads done
    commit();
    const int kbn = (kt + 1 < numT) ? (kt + 1) * 32 : 0;  // harmless reload
    prefetch(kbn);     // next tile: global latency hides behind MFMA phase
    __syncthreads();   // staging visible

    // cache all A fragments once per tile (dedup across pb)
    bf16x8 afr[APL][4];
    #pragma unroll
    for (int pa = 0; pa < APL; ++pa)
      #pragma unroll
      for (int i = 0; i < 4; ++i)
        afr[pa][i] =
            *(const bf16x8*)(&As[pa][(wm + i * 16 + l16) * LDW + quad * 8]);

    #pragma unroll
    for (int pb = 0; pb < 3; ++pb) {
      bf16x8 bfr[4];
      #pragma unroll
      for (int j = 0; j < 4; ++j)
        bfr[j] =
            *(const bf16x8*)(&Bs[pb][(wn + j * 16 + l16) * LDW + quad * 8]);
      const int pamax = AF32 ? (2 - pb) : 0;  // pairs with pa+pb<=2
      #pragma unroll
      for (int pa = 0; pa < APL; ++pa) {
        if (pa > pamax) break;
        #pragma unroll
        for (int i = 0; i < 4; ++i)
          #pragma unroll
          for (int j = 0; j < 4; ++j)
            acc[i][j] = __builtin_amdgcn_mfma_f32_16x16x32_bf16(
                afr[pa][i], bfr[j], acc[i][j], 0, 0, 0);
      }
    }
  }

  // epilogue: C/D layout col=lane&15, row=quad*4+reg (m89/m91-verified)
  #pragma unroll
  for (int j = 0; j < 4; ++j) {
    const long col = n0 + wn + j * 16 + l16;
    const float bvv = bias[col];
    #pragma unroll
    for (int i = 0; i < 4; ++i) {
      const long row0 = m0 + wm + i * 16 + quad * 4;
      #pragma unroll
      for (int g = 0; g < 4; ++g)
        C[(row0 + g) * (long)N + col] = acc[i][j][g] + bvv;
    }
  }
}

// LIF scan, fp32 in -> bf16 spikes out (spikes {0,1} exact in bf16).
__global__ __launch_bounds__(256) void lif_scan_bf16(const float* __restrict__ I,
                                                     bf16_t* __restrict__ S) {
  int idx = blockIdx.x * 256 + threadIdx.x;
  float v = 0.f, cur = 0.f;
  #pragma unroll
  for (int t = 0; t < TT; ++t) {
    float inp = I[(long)t * (TB * TH) + idx];
    float vd = fmaf(0.05f, cur - v, v);
    float id = cur - 0.2f * cur;
    float s = (vd > 1.0f) ? 1.0f : 0.f;
    v = (1.0f - s) * vd;
    cur = id + inp;
    S[(long)t * (TB * TH) + idx] = (bf16_t)s;
  }
}

// GEMM3: one wave per row; I3[r][o] = S2[r][:] . Wout[o][:] + bout[o]
__global__ __launch_bounds__(256) void gemm3_kernel(
    const bf16_t* __restrict__ S2, const float* __restrict__ Wout,
    const float* __restrict__ bout, float* __restrict__ I3) {
  int wv = (blockIdx.x * blockDim.x + threadIdx.x) >> 6;
  int lane = threadIdx.x & 63;
  if (wv >= TM) return;
  const bf16_t* srow = S2 + (long)wv * TH;
  float acc[TOUT];
  #pragma unroll
  for (int o = 0; o < TOUT; ++o) acc[o] = 0.f;
  for (int k = lane; k < TH; k += 64) {
    float s = (float)srow[k];
    #pragma unroll
    for (int o = 0; o < TOUT; ++o) acc[o] = fmaf(s, Wout[o * TH + k], acc[o]);
  }
  #pragma unroll
  for (int off = 32; off > 0; off >>= 1)
    #pragma unroll
    for (int o = 0; o < TOUT; ++o) acc[o] += __shfl_down(acc[o], off, 64);
  if (lane == 0) {
    #pragma unroll
    for (int o = 0; o < TOUT; ++o) I3[(long)wv * TOUT + o] = acc[o] + bout[o];
  }
}

__global__ __launch_bounds__(256) void scan_out(const float* __restrict__ I3,
                                                float* __restrict__ out) {
  int idx = blockIdx.x * blockDim.x + threadIdx.x;
  if (idx >= TB * TOUT) return;
  float v = 0.f, cur = 0.f, cnt = 0.f;
  #pragma unroll
  for (int t = 0; t < TT; ++t) {
    float inp = I3[(long)t * (TB * TOUT) + idx];
    float vd = fmaf(0.05f, cur - v, v);
    float id = cur - 0.2f * cur;
    float s = (vd > 1.0f) ? 1.0f : 0.f;
    v = (1.0f - s) * vd;
    cur = id + inp;
    cnt += s;
  }
  out[idx] = cnt;
}

extern "C" void kernel_launch(void* const* d_in, const int* in_sizes, int n_in,
                              void* d_out, int out_size, void* d_ws,
                              size_t ws_size, hipStream_t stream) {
  const float* x    = (const float*)d_in[0];  // (256,32,2312)
  const float* W1   = (const float*)d_in[1];  // (1024,2312)
  const float* b1   = (const float*)d_in[2];
  const float* W2   = (const float*)d_in[3];  // (1024,1024)
  const float* b2   = (const float*)d_in[4];
  const float* Wout = (const float*)d_in[5];  // (10,1024)
  const float* bout = (const float*)d_in[6];

  // ws: W1p 14.55MB | W2p 6.29MB | bufI 33.55MB | S1 16.78MB | buf3 0.33MB
  // S2 (16.78MB) ALIASES W1p/W2p: planes are last read by GEMM2, S2 is
  // written by the later scan (stream-sequential => safe; rebuilt each call).
  bf16_t* W1p  = (bf16_t*)d_ws;
  bf16_t* W2p  = W1p + 3L * TH * KP1;
  float*  bufI = (float*)(W2p + 3L * TH * TH);
  bf16_t* S1   = (bf16_t*)(bufI + (long)TM * TH);
  float*  buf3 = (float*)(S1 + (long)TM * TH);
  bf16_t* S2   = (bf16_t*)d_ws;

  split_w<<<dim3(3, TH), 256, 0, stream>>>(W1, W1p, (long)TH * KP1, TIN, KP1);
  split_w<<<dim3(1, TH), 256, 0, stream>>>(W2, W2p, (long)TH * TH, TH, TH);

  // GEMM1: row r=(t,b): x offset = t*2312 + b*(32*2312)
  snn_gemm<true><<<dim3(TM / 128, TH / 128), 256, 0, stream>>>(
      x, nullptr, (long)TIN, (long)TT * TIN, W1p, (long)TH * KP1, KP1, TIN, b1,
      bufI, TH);

  lif_scan_bf16<<<(TB * TH) / 256, 256, 0, stream>>>(bufI, S1);

  // GEMM2: S1 row-major [8192][1024]: sT=256*1024, sB=1024
  snn_gemm<false><<<dim3(TM / 128, TH / 128), 256, 0, stream>>>(
      nullptr, S1, (long)TB * TH, (long)TH, W2p, (long)TH * TH, TH, TH, b2,
      bufI, TH);

  lif_scan_bf16<<<(TB * TH) / 256, 256, 0, stream>>>(bufI, S2);

  gemm3_kernel<<<(TM * 64) / 256, 256, 0, stream>>>(S2, Wout, bout, buf3);

  scan_out<<<(TB * TOUT + 255) / 256, 256, 0, stream>>>(buf3, (float*)d_out);
}